// Round 16
// baseline (110.875 us; speedup 1.0000x reference)
//
#include <hip/hip_runtime.h>
#include <stdint.h>

#define N_NODES 50000
#define N_EDGES 800000
#define IN_DIM  128
#define HID_DIM 64
#define OUT_DIM 64

#define NPB     256                         // partition blocks
#define EPB     (N_EDGES / NPB)             // 3125 edges per block (exact)
#define BSH     9                           // bucket shift: 512 nodes/bucket
#define NB      ((N_NODES + 511) >> BSH)    // 98 buckets
#define BCAP    10240                       // per-bucket capacity (mean 8192 + 22 sigma)
#define GEMM_BLOCKS ((N_NODES + 63) / 64)   // 782

// ---------------------------------------------------------------------------
// bf16 helpers (RNE pack, bit-shift unpack; accumulate in fp32)
// ---------------------------------------------------------------------------
__device__ __forceinline__ uint32_t f2bf(float f) {
    uint32_t u = __float_as_uint(f);
    return (u + 0x7FFFu + ((u >> 16) & 1u)) >> 16;
}
__device__ __forceinline__ uint32_t pack2bf(float a, float b) {
    return f2bf(a) | (f2bf(b) << 16);
}
__device__ __forceinline__ float bflo(uint32_t v) { return __uint_as_float(v << 16); }
__device__ __forceinline__ float bfhi(uint32_t v) { return __uint_as_float(v & 0xFFFF0000u); }

// ---------------------------------------------------------------------------
// k_part2: FUSED histogram + chunk reservation + partition.
// ---------------------------------------------------------------------------
__global__ __launch_bounds__(256) void k_part2(const int* __restrict__ ei,
                                               int* __restrict__ bucketcnt,
                                               int* __restrict__ brec) {
    __shared__ int hist[NB];
    __shared__ int cursor[NB];
    const int blk = blockIdx.x, tid = threadIdx.x;
    if (tid < NB) hist[tid] = 0;
    __syncthreads();
    const int e0 = blk * EPB;
    for (int e = e0 + tid; e < e0 + EPB; e += 256)
        atomicAdd(&hist[ei[N_EDGES + e] >> BSH], 1);
    __syncthreads();
    if (tid < NB) {
        int c = hist[tid];
        int base = (c > 0) ? atomicAdd(&bucketcnt[tid], c) : 0;
        cursor[tid] = tid * BCAP + base;
    }
    __syncthreads();
    for (int e = e0 + tid; e < e0 + EPB; e += 256) {
        int s = ei[e];
        int d = ei[N_EDGES + e];
        int b = d >> BSH;
        int pos = atomicAdd(&cursor[b], 1);
        if (pos < (b + 1) * BCAP)                       // overflow guard
            brec[pos] = s | ((d & 511) << 16);
    }
}

// ---------------------------------------------------------------------------
// k_csrgemm: ONE kernel, two independent roles running concurrently:
//   blocks [0, NB):          per-bucket CSR finalize (rowstart/rowcnt/dinv/edata)
//   blocks [NB, NB+782):     GEMM1 tile: hsb1[row,64] = bf16(X[row,:] @ W1)
// (UNSCALED h1 — per-edge dinv[src] applied later in the gathers, so the
// GEMM role has no dependency on the CSR role.)
// ---------------------------------------------------------------------------
__global__ __launch_bounds__(256) void k_csrgemm(const int* __restrict__ brec,
                                                 const int* __restrict__ bucketcnt,
                                                 int* __restrict__ rowstart,
                                                 int* __restrict__ rowcnt,
                                                 float* __restrict__ dinv,
                                                 unsigned short* __restrict__ edata,
                                                 const float* __restrict__ X,
                                                 const float* __restrict__ W1,
                                                 uint32_t* __restrict__ hsb1,
                                                 int n) {
    __shared__ __align__(16) char smem[45088];   // union: csr 44.1KB | gemm 32KB
    const int tid = threadIdx.x;

    if (blockIdx.x < NB) {
        // ================= CSR finalize role =================
        int* sbuf   = (int*)smem;                // [BCAP] 40KB
        int* deg    = sbuf + BCAP;               // [512]
        int* segoff = deg + 512;                 // [512]
        int* wt     = segoff + 512;              // [4]
        const int b = blockIdx.x;
        const int lo = b << BSH;
        const int cbase = b * BCAP;
        int cnt = bucketcnt[b];
        if (cnt > BCAP) cnt = BCAP;

        deg[tid] = 0;
        deg[tid + 256] = 0;
        for (int j = tid; j < cnt; j += 256) sbuf[j] = brec[cbase + j];
        __syncthreads();

        for (int j = tid; j < cnt; j += 256) atomicAdd(&deg[sbuf[j] >> 16], 1);
        __syncthreads();

        const int i0 = tid << 1;
        const int d0 = deg[i0], d1 = deg[i0 + 1];
        const int s = d0 + d1;
        int wid = tid >> 6, lane = tid & 63;
        int incl = s;
        for (int o = 1; o < 64; o <<= 1) {
            int v = __shfl_up(incl, o, 64);
            if (lane >= o) incl += v;
        }
        if (lane == 63) wt[wid] = incl;
        __syncthreads();
        int woff = 0;
        for (int w = 0; w < wid; ++w) woff += wt[w];
        const int excl = woff + incl - s;

        segoff[i0]     = excl;
        segoff[i0 + 1] = excl + d0;

        if (lo + i0 < N_NODES) {
            rowstart[lo + i0] = cbase + excl;
            rowcnt[lo + i0]   = d0;
            dinv[lo + i0] = rsqrtf((float)d0 + 1.0f);
        }
        if (lo + i0 + 1 < N_NODES) {
            rowstart[lo + i0 + 1] = cbase + excl + d0;
            rowcnt[lo + i0 + 1]   = d1;
            dinv[lo + i0 + 1] = rsqrtf((float)d1 + 1.0f);
        }
        __syncthreads();

        for (int j = tid; j < cnt; j += 256) {
            int rec = sbuf[j];
            int pos = cbase + atomicAdd(&segoff[rec >> 16], 1);
            edata[pos] = (unsigned short)(rec & 0xFFFF);
        }
        return;
    }

    // ================= GEMM1 role (K = 128) =================
    constexpr int QK = IN_DIM / 4;               // 32
    float4* Ws = (float4*)smem;                  // [IN_DIM*16] = 32KB
    const int row0 = (blockIdx.x - NB) * 64;

    for (int f = tid; f < IN_DIM * 16; f += 256) Ws[f] = ((const float4*)W1)[f];
    __syncthreads();

    const int c4 = tid & 15;
    const int r0 = row0 + ((tid >> 4) << 2);
    const float4* Xq = (const float4*)X;

    float4 a0 = make_float4(0.f, 0.f, 0.f, 0.f);
    float4 a1 = a0, a2 = a0, a3 = a0;

    if (r0 + 3 < n) {
        const float4* xp0 = Xq + (size_t)r0 * QK;
        const float4* xp1 = xp0 + QK;
        const float4* xp2 = xp1 + QK;
        const float4* xp3 = xp2 + QK;
#pragma unroll 4
        for (int k4 = 0; k4 < QK; ++k4) {
            const float4 x0 = xp0[k4];
            const float4 x1 = xp1[k4];
            const float4 x2 = xp2[k4];
            const float4 x3 = xp3[k4];
            const float4 w0 = Ws[(k4 * 4 + 0) * 16 + c4];
            const float4 w1 = Ws[(k4 * 4 + 1) * 16 + c4];
            const float4 w2 = Ws[(k4 * 4 + 2) * 16 + c4];
            const float4 w3 = Ws[(k4 * 4 + 3) * 16 + c4];
            a0.x += x0.x*w0.x + x0.y*w1.x + x0.z*w2.x + x0.w*w3.x;
            a0.y += x0.x*w0.y + x0.y*w1.y + x0.z*w2.y + x0.w*w3.y;
            a0.z += x0.x*w0.z + x0.y*w1.z + x0.z*w2.z + x0.w*w3.z;
            a0.w += x0.x*w0.w + x0.y*w1.w + x0.z*w2.w + x0.w*w3.w;
            a1.x += x1.x*w0.x + x1.y*w1.x + x1.z*w2.x + x1.w*w3.x;
            a1.y += x1.x*w0.y + x1.y*w1.y + x1.z*w2.y + x1.w*w3.y;
            a1.z += x1.x*w0.z + x1.y*w1.z + x1.z*w2.z + x1.w*w3.z;
            a1.w += x1.x*w0.w + x1.y*w1.w + x1.z*w2.w + x1.w*w3.w;
            a2.x += x2.x*w0.x + x2.y*w1.x + x2.z*w2.x + x2.w*w3.x;
            a2.y += x2.x*w0.y + x2.y*w1.y + x2.z*w2.y + x2.w*w3.y;
            a2.z += x2.x*w0.z + x2.y*w1.z + x2.z*w2.z + x2.w*w3.z;
            a2.w += x2.x*w0.w + x2.y*w1.w + x2.z*w2.w + x2.w*w3.w;
            a3.x += x3.x*w0.x + x3.y*w1.x + x3.z*w2.x + x3.w*w3.x;
            a3.y += x3.x*w0.y + x3.y*w1.y + x3.z*w2.y + x3.w*w3.y;
            a3.z += x3.x*w0.z + x3.y*w1.z + x3.z*w2.z + x3.w*w3.z;
            a3.w += x3.x*w0.w + x3.y*w1.w + x3.z*w2.w + x3.w*w3.w;
        }
        ((uint2*)hsb1)[((size_t)(r0 + 0) * 32 + c4 * 2) >> 1] = make_uint2(pack2bf(a0.x, a0.y), pack2bf(a0.z, a0.w));
        ((uint2*)hsb1)[((size_t)(r0 + 1) * 32 + c4 * 2) >> 1] = make_uint2(pack2bf(a1.x, a1.y), pack2bf(a1.z, a1.w));
        ((uint2*)hsb1)[((size_t)(r0 + 2) * 32 + c4 * 2) >> 1] = make_uint2(pack2bf(a2.x, a2.y), pack2bf(a2.z, a2.w));
        ((uint2*)hsb1)[((size_t)(r0 + 3) * 32 + c4 * 2) >> 1] = make_uint2(pack2bf(a3.x, a3.y), pack2bf(a3.z, a3.w));
    } else {
        const float4 z = make_float4(0.f, 0.f, 0.f, 0.f);
        for (int k4 = 0; k4 < QK; ++k4) {
            const float4 x0 = (r0 + 0 < n) ? Xq[(size_t)(r0 + 0) * QK + k4] : z;
            const float4 x1 = (r0 + 1 < n) ? Xq[(size_t)(r0 + 1) * QK + k4] : z;
            const float4 x2 = (r0 + 2 < n) ? Xq[(size_t)(r0 + 2) * QK + k4] : z;
            const float4 x3 = (r0 + 3 < n) ? Xq[(size_t)(r0 + 3) * QK + k4] : z;
            const float4 w0 = Ws[(k4 * 4 + 0) * 16 + c4];
            const float4 w1 = Ws[(k4 * 4 + 1) * 16 + c4];
            const float4 w2 = Ws[(k4 * 4 + 2) * 16 + c4];
            const float4 w3 = Ws[(k4 * 4 + 3) * 16 + c4];
            a0.x += x0.x*w0.x + x0.y*w1.x + x0.z*w2.x + x0.w*w3.x;
            a0.y += x0.x*w0.y + x0.y*w1.y + x0.z*w2.y + x0.w*w3.y;
            a0.z += x0.x*w0.z + x0.y*w1.z + x0.z*w2.z + x0.w*w3.z;
            a0.w += x0.x*w0.w + x0.y*w1.w + x0.z*w2.w + x0.w*w3.w;
            a1.x += x1.x*w0.x + x1.y*w1.x + x1.z*w2.x + x1.w*w3.x;
            a1.y += x1.x*w0.y + x1.y*w1.y + x1.z*w2.y + x1.w*w3.y;
            a1.z += x1.x*w0.z + x1.y*w1.z + x1.z*w2.z + x1.w*w3.z;
            a1.w += x1.x*w0.w + x1.y*w1.w + x1.z*w2.w + x1.w*w3.w;
            a2.x += x2.x*w0.x + x2.y*w1.x + x2.z*w2.x + x2.w*w3.x;
            a2.y += x2.x*w0.y + x2.y*w1.y + x2.z*w2.y + x2.w*w3.y;
            a2.z += x2.x*w0.z + x2.y*w1.z + x2.z*w2.z + x2.w*w3.z;
            a2.w += x2.x*w0.w + x2.y*w1.w + x2.z*w2.w + x2.w*w3.w;
            a3.x += x3.x*w0.x + x3.y*w1.x + x3.z*w2.x + x3.w*w3.x;
            a3.y += x3.x*w0.y + x3.y*w1.y + x3.z*w2.y + x3.w*w3.y;
            a3.z += x3.x*w0.z + x3.y*w1.z + x3.z*w2.z + x3.w*w3.z;
            a3.w += x3.x*w0.w + x3.y*w1.w + x3.z*w2.w + x3.w*w3.w;
        }
        if (r0 + 0 < n) ((uint2*)hsb1)[((size_t)(r0 + 0) * 32 + c4 * 2) >> 1] = make_uint2(pack2bf(a0.x, a0.y), pack2bf(a0.z, a0.w));
        if (r0 + 1 < n) ((uint2*)hsb1)[((size_t)(r0 + 1) * 32 + c4 * 2) >> 1] = make_uint2(pack2bf(a1.x, a1.y), pack2bf(a1.z, a1.w));
        if (r0 + 2 < n) ((uint2*)hsb1)[((size_t)(r0 + 2) * 32 + c4 * 2) >> 1] = make_uint2(pack2bf(a2.x, a2.y), pack2bf(a2.z, a2.w));
        if (r0 + 3 < n) ((uint2*)hsb1)[((size_t)(r0 + 3) * 32 + c4 * 2) >> 1] = make_uint2(pack2bf(a3.x, a3.y), pack2bf(a3.z, a3.w));
    }
}

// ---------------------------------------------------------------------------
// k_gg2: FUSED gather1+ReLU (phase A, unroll-8, per-edge dinv[src] weight,
// results to LDS) and GEMM2 (phase B, W2 in LDS, raw bf16 output).
// ---------------------------------------------------------------------------
__global__ __launch_bounds__(256) void k_gg2(const int* __restrict__ rowstart,
                                             const int* __restrict__ rowcnt,
                                             const unsigned short* __restrict__ edata,
                                             const uint32_t* __restrict__ hsb1,
                                             const float* __restrict__ dinv,
                                             const float* __restrict__ b1v,
                                             const float* __restrict__ W2,
                                             uint32_t* __restrict__ hsb2) {
    __shared__ float W2s[64 * 64];            // 16KB row-major [k][c]
    __shared__ float a1s[32][68];             // 8.7KB padded
    const int tid = threadIdx.x;

    for (int f = tid; f < 1024; f += 256)
        ((float4*)W2s)[f] = ((const float4*)W2)[f];

    // ---- phase A: gather (msg = dinv[s]*h1[s]) + self + bias + relu -> a1s
    const int nl = tid >> 3;
    const int lane = tid & 7;
    const int node = blockIdx.x * 32 + nl;
    if (node < N_NODES) {
        int start = rowstart[node];
        int end   = start + rowcnt[node];
        const uint4* hq = (const uint4*)hsb1;
        float a0 = 0.f, a1 = 0.f, a2 = 0.f, a3 = 0.f,
              a4 = 0.f, a5 = 0.f, a6 = 0.f, a7 = 0.f;
        int j = start;
        for (; j + 8 <= end; j += 8) {
            const int s0 = edata[j + 0];
            const int s1 = edata[j + 1];
            const int s2 = edata[j + 2];
            const int s3 = edata[j + 3];
            const int s4 = edata[j + 4];
            const int s5 = edata[j + 5];
            const int s6 = edata[j + 6];
            const int s7 = edata[j + 7];
            const float g0 = dinv[s0];
            const float g1 = dinv[s1];
            const float g2 = dinv[s2];
            const float g3 = dinv[s3];
            const float g4 = dinv[s4];
            const float g5 = dinv[s5];
            const float g6 = dinv[s6];
            const float g7 = dinv[s7];
            const uint4 v0 = hq[(size_t)s0 * 8 + lane];
            const uint4 v1 = hq[(size_t)s1 * 8 + lane];
            const uint4 v2 = hq[(size_t)s2 * 8 + lane];
            const uint4 v3 = hq[(size_t)s3 * 8 + lane];
            const uint4 v4 = hq[(size_t)s4 * 8 + lane];
            const uint4 v5 = hq[(size_t)s5 * 8 + lane];
            const uint4 v6 = hq[(size_t)s6 * 8 + lane];
            const uint4 v7 = hq[(size_t)s7 * 8 + lane];
            a0 += g0*bflo(v0.x) + g1*bflo(v1.x) + g2*bflo(v2.x) + g3*bflo(v3.x)
                + g4*bflo(v4.x) + g5*bflo(v5.x) + g6*bflo(v6.x) + g7*bflo(v7.x);
            a1 += g0*bfhi(v0.x) + g1*bfhi(v1.x) + g2*bfhi(v2.x) + g3*bfhi(v3.x)
                + g4*bfhi(v4.x) + g5*bfhi(v5.x) + g6*bfhi(v6.x) + g7*bfhi(v7.x);
            a2 += g0*bflo(v0.y) + g1*bflo(v1.y) + g2*bflo(v2.y) + g3*bflo(v3.y)
                + g4*bflo(v4.y) + g5*bflo(v5.y) + g6*bflo(v6.y) + g7*bflo(v7.y);
            a3 += g0*bfhi(v0.y) + g1*bfhi(v1.y) + g2*bfhi(v2.y) + g3*bfhi(v3.y)
                + g4*bfhi(v4.y) + g5*bfhi(v5.y) + g6*bfhi(v6.y) + g7*bfhi(v7.y);
            a4 += g0*bflo(v0.z) + g1*bflo(v1.z) + g2*bflo(v2.z) + g3*bflo(v3.z)
                + g4*bflo(v4.z) + g5*bflo(v5.z) + g6*bflo(v6.z) + g7*bflo(v7.z);
            a5 += g0*bfhi(v0.z) + g1*bfhi(v1.z) + g2*bfhi(v2.z) + g3*bfhi(v3.z)
                + g4*bfhi(v4.z) + g5*bfhi(v5.z) + g6*bfhi(v6.z) + g7*bfhi(v7.z);
            a6 += g0*bflo(v0.w) + g1*bflo(v1.w) + g2*bflo(v2.w) + g3*bflo(v3.w)
                + g4*bflo(v4.w) + g5*bflo(v5.w) + g6*bflo(v6.w) + g7*bflo(v7.w);
            a7 += g0*bfhi(v0.w) + g1*bfhi(v1.w) + g2*bfhi(v2.w) + g3*bfhi(v3.w)
                + g4*bfhi(v4.w) + g5*bfhi(v5.w) + g6*bfhi(v6.w) + g7*bfhi(v7.w);
        }
        for (; j < end; ++j) {
            const int s = edata[j];
            const float g = dinv[s];
            const uint4 v = hq[(size_t)s * 8 + lane];
            a0 += g * bflo(v.x); a1 += g * bfhi(v.x);
            a2 += g * bflo(v.y); a3 += g * bfhi(v.y);
            a4 += g * bflo(v.z); a5 += g * bfhi(v.z);
            a6 += g * bflo(v.w); a7 += g * bfhi(v.w);
        }
        const float di = dinv[node];
        {   // self loop: + dinv[node]*h1[node]
            const uint4 v = hq[(size_t)node * 8 + lane];
            a0 += di * bflo(v.x); a1 += di * bfhi(v.x);
            a2 += di * bflo(v.y); a3 += di * bfhi(v.y);
            a4 += di * bflo(v.z); a5 += di * bfhi(v.z);
            a6 += di * bflo(v.w); a7 += di * bfhi(v.w);
        }
        const float4 b0 = *reinterpret_cast<const float4*>(&b1v[lane * 8]);
        const float4 b1 = *reinterpret_cast<const float4*>(&b1v[lane * 8 + 4]);
        float4 o0, o1;
        o0.x = fmaxf(a0 * di + b0.x, 0.f);
        o0.y = fmaxf(a1 * di + b0.y, 0.f);
        o0.z = fmaxf(a2 * di + b0.z, 0.f);
        o0.w = fmaxf(a3 * di + b0.w, 0.f);
        o1.x = fmaxf(a4 * di + b1.x, 0.f);
        o1.y = fmaxf(a5 * di + b1.y, 0.f);
        o1.z = fmaxf(a6 * di + b1.z, 0.f);
        o1.w = fmaxf(a7 * di + b1.w, 0.f);
        *reinterpret_cast<float4*>(&a1s[nl][lane * 8])     = o0;
        *reinterpret_cast<float4*>(&a1s[nl][lane * 8 + 4]) = o1;
    }

    __syncthreads();

    // ---- phase B: hs2[node] = a1s[node] @ W2 (raw), packed bf16 ----
    const int gnode = blockIdx.x * 32 + (tid >> 3);
    if (gnode < N_NODES) {
        const int c8 = (tid & 7) * 8;
        const int nb = tid >> 3;
        float c0 = 0.f, c1 = 0.f, c2 = 0.f, c3 = 0.f,
              c4 = 0.f, c5 = 0.f, c6 = 0.f, c7 = 0.f;
#pragma unroll 8
        for (int k = 0; k < 64; ++k) {
            const float a = a1s[nb][k];
            const float4 w0 = *(const float4*)&W2s[k * 64 + c8];
            const float4 w1 = *(const float4*)&W2s[k * 64 + c8 + 4];
            c0 += a * w0.x; c1 += a * w0.y; c2 += a * w0.z; c3 += a * w0.w;
            c4 += a * w1.x; c5 += a * w1.y; c6 += a * w1.z; c7 += a * w1.w;
        }
        uint4 o;
        o.x = pack2bf(c0, c1);
        o.y = pack2bf(c2, c3);
        o.z = pack2bf(c4, c5);
        o.w = pack2bf(c6, c7);
        ((uint4*)hsb2)[(size_t)gnode * 8 + (tid & 7)] = o;
    }
}

// ---------------------------------------------------------------------------
// k_gather: layer-2 aggregate -> out (unroll-8, per-edge dinv[src] weight).
// out[i] = dinv[i]*(sum_j dinv[j]*h2[j] + dinv[i]*h2[i]) + b2
// ---------------------------------------------------------------------------
__global__ __launch_bounds__(256) void k_gather(const int* __restrict__ rowstart,
                                                const int* __restrict__ rowcnt,
                                                const unsigned short* __restrict__ edata,
                                                const uint32_t* __restrict__ hsb,
                                                const float* __restrict__ dinv,
                                                const float* __restrict__ bias,
                                                float* __restrict__ out) {
    int node = blockIdx.x * 32 + (threadIdx.x >> 3);
    int lane = threadIdx.x & 7;
    if (node >= N_NODES) return;

    int start = rowstart[node];
    int end   = start + rowcnt[node];

    const uint4* hq = (const uint4*)hsb;
    float a0 = 0.f, a1 = 0.f, a2 = 0.f, a3 = 0.f,
          a4 = 0.f, a5 = 0.f, a6 = 0.f, a7 = 0.f;

    int j = start;
    for (; j + 8 <= end; j += 8) {
        const int s0 = edata[j + 0];
        const int s1 = edata[j + 1];
        const int s2 = edata[j + 2];
        const int s3 = edata[j + 3];
        const int s4 = edata[j + 4];
        const int s5 = edata[j + 5];
        const int s6 = edata[j + 6];
        const int s7 = edata[j + 7];
        const float g0 = dinv[s0];
        const float g1 = dinv[s1];
        const float g2 = dinv[s2];
        const float g3 = dinv[s3];
        const float g4 = dinv[s4];
        const float g5 = dinv[s5];
        const float g6 = dinv[s6];
        const float g7 = dinv[s7];
        const uint4 v0 = hq[(size_t)s0 * 8 + lane];
        const uint4 v1 = hq[(size_t)s1 * 8 + lane];
        const uint4 v2 = hq[(size_t)s2 * 8 + lane];
        const uint4 v3 = hq[(size_t)s3 * 8 + lane];
        const uint4 v4 = hq[(size_t)s4 * 8 + lane];
        const uint4 v5 = hq[(size_t)s5 * 8 + lane];
        const uint4 v6 = hq[(size_t)s6 * 8 + lane];
        const uint4 v7 = hq[(size_t)s7 * 8 + lane];
        a0 += g0*bflo(v0.x) + g1*bflo(v1.x) + g2*bflo(v2.x) + g3*bflo(v3.x)
            + g4*bflo(v4.x) + g5*bflo(v5.x) + g6*bflo(v6.x) + g7*bflo(v7.x);
        a1 += g0*bfhi(v0.x) + g1*bfhi(v1.x) + g2*bfhi(v2.x) + g3*bfhi(v3.x)
            + g4*bfhi(v4.x) + g5*bfhi(v5.x) + g6*bfhi(v6.x) + g7*bfhi(v7.x);
        a2 += g0*bflo(v0.y) + g1*bflo(v1.y) + g2*bflo(v2.y) + g3*bflo(v3.y)
            + g4*bflo(v4.y) + g5*bflo(v5.y) + g6*bflo(v6.y) + g7*bflo(v7.y);
        a3 += g0*bfhi(v0.y) + g1*bfhi(v1.y) + g2*bfhi(v2.y) + g3*bfhi(v3.y)
            + g4*bfhi(v4.y) + g5*bfhi(v5.y) + g6*bfhi(v6.y) + g7*bfhi(v7.y);
        a4 += g0*bflo(v0.z) + g1*bflo(v1.z) + g2*bflo(v2.z) + g3*bflo(v3.z)
            + g4*bflo(v4.z) + g5*bflo(v5.z) + g6*bflo(v6.z) + g7*bflo(v7.z);
        a5 += g0*bfhi(v0.z) + g1*bfhi(v1.z) + g2*bfhi(v2.z) + g3*bfhi(v3.z)
            + g4*bfhi(v4.z) + g5*bfhi(v5.z) + g6*bfhi(v6.z) + g7*bfhi(v7.z);
        a6 += g0*bflo(v0.w) + g1*bflo(v1.w) + g2*bflo(v2.w) + g3*bflo(v3.w)
            + g4*bflo(v4.w) + g5*bflo(v5.w) + g6*bflo(v6.w) + g7*bflo(v7.w);
        a7 += g0*bfhi(v0.w) + g1*bfhi(v1.w) + g2*bfhi(v2.w) + g3*bfhi(v3.w)
            + g4*bfhi(v4.w) + g5*bfhi(v5.w) + g6*bfhi(v6.w) + g7*bfhi(v7.w);
    }
    for (; j < end; ++j) {
        const int s = edata[j];
        const float g = dinv[s];
        const uint4 v = hq[(size_t)s * 8 + lane];
        a0 += g * bflo(v.x); a1 += g * bfhi(v.x);
        a2 += g * bflo(v.y); a3 += g * bfhi(v.y);
        a4 += g * bflo(v.z); a5 += g * bfhi(v.z);
        a6 += g * bflo(v.w); a7 += g * bfhi(v.w);
    }
    const float di = dinv[node];
    {   // self loop
        const uint4 v = hq[(size_t)node * 8 + lane];
        a0 += di * bflo(v.x); a1 += di * bfhi(v.x);
        a2 += di * bflo(v.y); a3 += di * bfhi(v.y);
        a4 += di * bflo(v.z); a5 += di * bfhi(v.z);
        a6 += di * bflo(v.w); a7 += di * bfhi(v.w);
    }

    const float4 b0 = *reinterpret_cast<const float4*>(&bias[lane * 8]);
    const float4 b1 = *reinterpret_cast<const float4*>(&bias[lane * 8 + 4]);
    float4 o0, o1;
    o0.x = a0 * di + b0.x;  o0.y = a1 * di + b0.y;
    o0.z = a2 * di + b0.z;  o0.w = a3 * di + b0.w;
    o1.x = a4 * di + b1.x;  o1.y = a5 * di + b1.y;
    o1.z = a6 * di + b1.z;  o1.w = a7 * di + b1.w;
    float4* op = (float4*)&out[(size_t)node * 64 + lane * 8];
    op[0] = o0;
    op[1] = o1;
}

extern "C" void kernel_launch(void* const* d_in, const int* in_sizes, int n_in,
                              void* d_out, int out_size, void* d_ws, size_t ws_size,
                              hipStream_t stream) {
    const float* x  = (const float*)d_in[0];
    const int*   ei = (const int*)d_in[1];    // [2, N_EDGES] int32
    const float* W1 = (const float*)d_in[2];
    const float* b1 = (const float*)d_in[3];
    const float* W2 = (const float*)d_in[4];
    const float* b2 = (const float*)d_in[5];
    float* out = (float*)d_out;

    // Workspace carve-up (16B-aligned chunks):
    //   bucketcnt[128] | brec[NB*BCAP] | rowstart[N+4] | rowcnt[N+4] |
    //   edata ushort[NB*BCAP] | dinv[N] | hsb1[N*32 u32] | hsb2[N*32 u32]
    int*            bucketcnt = (int*)d_ws;
    int*            brec      = bucketcnt + 128;
    int*            rowstart  = brec + NB * BCAP;              // 1,003,520
    int*            rowcnt    = rowstart + (N_NODES + 4);
    unsigned short* edata     = (unsigned short*)(rowcnt + (N_NODES + 4));
    float*          dinv      = (float*)(edata + NB * BCAP);   // even count -> aligned
    uint32_t*       hsb1      = (uint32_t*)(dinv + N_NODES);   // bf16 [N][64]
    uint32_t*       hsb2      = hsb1 + (size_t)N_NODES * 32;   // bf16 [N][64]

    // --- CSR build + layer-1 GEMM (concurrent roles in one kernel) ---
    hipMemsetAsync(bucketcnt, 0, 128 * sizeof(int), stream);
    k_part2<<<NPB, 256, 0, stream>>>(ei, bucketcnt, brec);
    k_csrgemm<<<NB + GEMM_BLOCKS, 256, 0, stream>>>(brec, bucketcnt, rowstart, rowcnt,
                                                    dinv, edata, x, W1, hsb1, N_NODES);

    // --- fused gather1 + ReLU + GEMM2 ---
    k_gg2<<<(N_NODES + 31) / 32, 256, 0, stream>>>(rowstart, rowcnt, edata, hsb1, dinv, b1, W2, hsb2);
    // --- layer 2 aggregate ---
    k_gather<<<(N_NODES + 31) / 32, 256, 0, stream>>>(rowstart, rowcnt, edata, hsb2, dinv, b2, out);
}

// Round 17
// 106.506 us; speedup vs baseline: 1.0410x; 1.0410x over previous
//
#include <hip/hip_runtime.h>
#include <stdint.h>

#define N_NODES 50000
#define N_EDGES 800000
#define IN_DIM  128
#define HID_DIM 64
#define OUT_DIM 64

#define NPB     256                         // partition blocks
#define EPB     (N_EDGES / NPB)             // 3125 edges per block (exact)
#define BSH     9                           // bucket shift: 512 nodes/bucket
#define NB      ((N_NODES + 511) >> BSH)    // 98 buckets
#define BCAP    10240                       // per-bucket capacity (mean 8192 + 22 sigma)
#define GEMM_BLOCKS ((N_NODES + 63) / 64)   // 782

// ---------------------------------------------------------------------------
// bf16 helpers (RNE pack, bit-shift unpack; accumulate in fp32)
// ---------------------------------------------------------------------------
__device__ __forceinline__ uint32_t f2bf(float f) {
    uint32_t u = __float_as_uint(f);
    return (u + 0x7FFFu + ((u >> 16) & 1u)) >> 16;
}
__device__ __forceinline__ uint32_t pack2bf(float a, float b) {
    return f2bf(a) | (f2bf(b) << 16);
}
__device__ __forceinline__ float bflo(uint32_t v) { return __uint_as_float(v << 16); }
__device__ __forceinline__ float bfhi(uint32_t v) { return __uint_as_float(v & 0xFFFF0000u); }

// ---------------------------------------------------------------------------
// k_zc: zero the per-bucket reservation cursors (replay-safe, proven cheap)
// ---------------------------------------------------------------------------
__global__ void k_zc(int* __restrict__ bucketcnt) {
    if (threadIdx.x < 128) bucketcnt[threadIdx.x] = 0;
}

// ---------------------------------------------------------------------------
// k_part2: FUSED histogram + chunk reservation + partition.
// ---------------------------------------------------------------------------
__global__ __launch_bounds__(256) void k_part2(const int* __restrict__ ei,
                                               int* __restrict__ bucketcnt,
                                               int* __restrict__ brec) {
    __shared__ int hist[NB];
    __shared__ int cursor[NB];
    const int blk = blockIdx.x, tid = threadIdx.x;
    if (tid < NB) hist[tid] = 0;
    __syncthreads();
    const int e0 = blk * EPB;
    for (int e = e0 + tid; e < e0 + EPB; e += 256)
        atomicAdd(&hist[ei[N_EDGES + e] >> BSH], 1);
    __syncthreads();
    if (tid < NB) {
        int c = hist[tid];
        int base = (c > 0) ? atomicAdd(&bucketcnt[tid], c) : 0;
        cursor[tid] = tid * BCAP + base;
    }
    __syncthreads();
    for (int e = e0 + tid; e < e0 + EPB; e += 256) {
        int s = ei[e];
        int d = ei[N_EDGES + e];
        int b = d >> BSH;
        int pos = atomicAdd(&cursor[b], 1);
        if (pos < (b + 1) * BCAP)                       // overflow guard
            brec[pos] = s | ((d & 511) << 16);
    }
}

// ---------------------------------------------------------------------------
// k_csrgemm: ONE kernel, two independent roles running concurrently:
//   blocks [0, NB):          per-bucket CSR finalize (rowstart/rowcnt/dinv/edata)
//   blocks [NB, NB+782):     GEMM1 tile: hsb1[row,64] = bf16(X[row,:] @ W1)
// (UNSCALED h1 — per-edge dinv[src] applied in k_gg2's gather only.)
// ---------------------------------------------------------------------------
__global__ __launch_bounds__(256) void k_csrgemm(const int* __restrict__ brec,
                                                 const int* __restrict__ bucketcnt,
                                                 int* __restrict__ rowstart,
                                                 int* __restrict__ rowcnt,
                                                 float* __restrict__ dinv,
                                                 unsigned short* __restrict__ edata,
                                                 const float* __restrict__ X,
                                                 const float* __restrict__ W1,
                                                 uint32_t* __restrict__ hsb1,
                                                 int n) {
    __shared__ __align__(16) char smem[45088];   // union: csr 44.1KB | gemm 32KB
    const int tid = threadIdx.x;

    if (blockIdx.x < NB) {
        // ================= CSR finalize role =================
        int* sbuf   = (int*)smem;                // [BCAP] 40KB
        int* deg    = sbuf + BCAP;               // [512]
        int* segoff = deg + 512;                 // [512]
        int* wt     = segoff + 512;              // [4]
        const int b = blockIdx.x;
        const int lo = b << BSH;
        const int cbase = b * BCAP;
        int cnt = bucketcnt[b];
        if (cnt > BCAP) cnt = BCAP;

        deg[tid] = 0;
        deg[tid + 256] = 0;
        for (int j = tid; j < cnt; j += 256) sbuf[j] = brec[cbase + j];
        __syncthreads();

        for (int j = tid; j < cnt; j += 256) atomicAdd(&deg[sbuf[j] >> 16], 1);
        __syncthreads();

        const int i0 = tid << 1;
        const int d0 = deg[i0], d1 = deg[i0 + 1];
        const int s = d0 + d1;
        int wid = tid >> 6, lane = tid & 63;
        int incl = s;
        for (int o = 1; o < 64; o <<= 1) {
            int v = __shfl_up(incl, o, 64);
            if (lane >= o) incl += v;
        }
        if (lane == 63) wt[wid] = incl;
        __syncthreads();
        int woff = 0;
        for (int w = 0; w < wid; ++w) woff += wt[w];
        const int excl = woff + incl - s;

        segoff[i0]     = excl;
        segoff[i0 + 1] = excl + d0;

        if (lo + i0 < N_NODES) {
            rowstart[lo + i0] = cbase + excl;
            rowcnt[lo + i0]   = d0;
            dinv[lo + i0] = rsqrtf((float)d0 + 1.0f);
        }
        if (lo + i0 + 1 < N_NODES) {
            rowstart[lo + i0 + 1] = cbase + excl + d0;
            rowcnt[lo + i0 + 1]   = d1;
            dinv[lo + i0 + 1] = rsqrtf((float)d1 + 1.0f);
        }
        __syncthreads();

        for (int j = tid; j < cnt; j += 256) {
            int rec = sbuf[j];
            int pos = cbase + atomicAdd(&segoff[rec >> 16], 1);
            edata[pos] = (unsigned short)(rec & 0xFFFF);
        }
        return;
    }

    // ================= GEMM1 role (K = 128) =================
    constexpr int QK = IN_DIM / 4;               // 32
    float4* Ws = (float4*)smem;                  // [IN_DIM*16] = 32KB
    const int row0 = (blockIdx.x - NB) * 64;

    for (int f = tid; f < IN_DIM * 16; f += 256) Ws[f] = ((const float4*)W1)[f];
    __syncthreads();

    const int c4 = tid & 15;
    const int r0 = row0 + ((tid >> 4) << 2);
    const float4* Xq = (const float4*)X;

    float4 a0 = make_float4(0.f, 0.f, 0.f, 0.f);
    float4 a1 = a0, a2 = a0, a3 = a0;

    if (r0 + 3 < n) {
        const float4* xp0 = Xq + (size_t)r0 * QK;
        const float4* xp1 = xp0 + QK;
        const float4* xp2 = xp1 + QK;
        const float4* xp3 = xp2 + QK;
#pragma unroll 4
        for (int k4 = 0; k4 < QK; ++k4) {
            const float4 x0 = xp0[k4];
            const float4 x1 = xp1[k4];
            const float4 x2 = xp2[k4];
            const float4 x3 = xp3[k4];
            const float4 w0 = Ws[(k4 * 4 + 0) * 16 + c4];
            const float4 w1 = Ws[(k4 * 4 + 1) * 16 + c4];
            const float4 w2 = Ws[(k4 * 4 + 2) * 16 + c4];
            const float4 w3 = Ws[(k4 * 4 + 3) * 16 + c4];
            a0.x += x0.x*w0.x + x0.y*w1.x + x0.z*w2.x + x0.w*w3.x;
            a0.y += x0.x*w0.y + x0.y*w1.y + x0.z*w2.y + x0.w*w3.y;
            a0.z += x0.x*w0.z + x0.y*w1.z + x0.z*w2.z + x0.w*w3.z;
            a0.w += x0.x*w0.w + x0.y*w1.w + x0.z*w2.w + x0.w*w3.w;
            a1.x += x1.x*w0.x + x1.y*w1.x + x1.z*w2.x + x1.w*w3.x;
            a1.y += x1.x*w0.y + x1.y*w1.y + x1.z*w2.y + x1.w*w3.y;
            a1.z += x1.x*w0.z + x1.y*w1.z + x1.z*w2.z + x1.w*w3.z;
            a1.w += x1.x*w0.w + x1.y*w1.w + x1.z*w2.w + x1.w*w3.w;
            a2.x += x2.x*w0.x + x2.y*w1.x + x2.z*w2.x + x2.w*w3.x;
            a2.y += x2.x*w0.y + x2.y*w1.y + x2.z*w2.y + x2.w*w3.y;
            a2.z += x2.x*w0.z + x2.y*w1.z + x2.z*w2.z + x2.w*w3.z;
            a2.w += x2.x*w0.w + x2.y*w1.w + x2.z*w2.w + x2.w*w3.w;
            a3.x += x3.x*w0.x + x3.y*w1.x + x3.z*w2.x + x3.w*w3.x;
            a3.y += x3.x*w0.y + x3.y*w1.y + x3.z*w2.y + x3.w*w3.y;
            a3.z += x3.x*w0.z + x3.y*w1.z + x3.z*w2.z + x3.w*w3.z;
            a3.w += x3.x*w0.w + x3.y*w1.w + x3.z*w2.w + x3.w*w3.w;
        }
        ((uint2*)hsb1)[((size_t)(r0 + 0) * 32 + c4 * 2) >> 1] = make_uint2(pack2bf(a0.x, a0.y), pack2bf(a0.z, a0.w));
        ((uint2*)hsb1)[((size_t)(r0 + 1) * 32 + c4 * 2) >> 1] = make_uint2(pack2bf(a1.x, a1.y), pack2bf(a1.z, a1.w));
        ((uint2*)hsb1)[((size_t)(r0 + 2) * 32 + c4 * 2) >> 1] = make_uint2(pack2bf(a2.x, a2.y), pack2bf(a2.z, a2.w));
        ((uint2*)hsb1)[((size_t)(r0 + 3) * 32 + c4 * 2) >> 1] = make_uint2(pack2bf(a3.x, a3.y), pack2bf(a3.z, a3.w));
    } else {
        const float4 z = make_float4(0.f, 0.f, 0.f, 0.f);
        for (int k4 = 0; k4 < QK; ++k4) {
            const float4 x0 = (r0 + 0 < n) ? Xq[(size_t)(r0 + 0) * QK + k4] : z;
            const float4 x1 = (r0 + 1 < n) ? Xq[(size_t)(r0 + 1) * QK + k4] : z;
            const float4 x2 = (r0 + 2 < n) ? Xq[(size_t)(r0 + 2) * QK + k4] : z;
            const float4 x3 = (r0 + 3 < n) ? Xq[(size_t)(r0 + 3) * QK + k4] : z;
            const float4 w0 = Ws[(k4 * 4 + 0) * 16 + c4];
            const float4 w1 = Ws[(k4 * 4 + 1) * 16 + c4];
            const float4 w2 = Ws[(k4 * 4 + 2) * 16 + c4];
            const float4 w3 = Ws[(k4 * 4 + 3) * 16 + c4];
            a0.x += x0.x*w0.x + x0.y*w1.x + x0.z*w2.x + x0.w*w3.x;
            a0.y += x0.x*w0.y + x0.y*w1.y + x0.z*w2.y + x0.w*w3.y;
            a0.z += x0.x*w0.z + x0.y*w1.z + x0.z*w2.z + x0.w*w3.z;
            a0.w += x0.x*w0.w + x0.y*w1.w + x0.z*w2.w + x0.w*w3.w;
            a1.x += x1.x*w0.x + x1.y*w1.x + x1.z*w2.x + x1.w*w3.x;
            a1.y += x1.x*w0.y + x1.y*w1.y + x1.z*w2.y + x1.w*w3.y;
            a1.z += x1.x*w0.z + x1.y*w1.z + x1.z*w2.z + x1.w*w3.z;
            a1.w += x1.x*w0.w + x1.y*w1.w + x1.z*w2.w + x1.w*w3.w;
            a2.x += x2.x*w0.x + x2.y*w1.x + x2.z*w2.x + x2.w*w3.x;
            a2.y += x2.x*w0.y + x2.y*w1.y + x2.z*w2.y + x2.w*w3.y;
            a2.z += x2.x*w0.z + x2.y*w1.z + x2.z*w2.z + x2.w*w3.z;
            a2.w += x2.x*w0.w + x2.y*w1.w + x2.z*w2.w + x2.w*w3.w;
            a3.x += x3.x*w0.x + x3.y*w1.x + x3.z*w2.x + x3.w*w3.x;
            a3.y += x3.x*w0.y + x3.y*w1.y + x3.z*w2.y + x3.w*w3.y;
            a3.z += x3.x*w0.z + x3.y*w1.z + x3.z*w2.z + x3.w*w3.z;
            a3.w += x3.x*w0.w + x3.y*w1.w + x3.z*w2.w + x3.w*w3.w;
        }
        if (r0 + 0 < n) ((uint2*)hsb1)[((size_t)(r0 + 0) * 32 + c4 * 2) >> 1] = make_uint2(pack2bf(a0.x, a0.y), pack2bf(a0.z, a0.w));
        if (r0 + 1 < n) ((uint2*)hsb1)[((size_t)(r0 + 1) * 32 + c4 * 2) >> 1] = make_uint2(pack2bf(a1.x, a1.y), pack2bf(a1.z, a1.w));
        if (r0 + 2 < n) ((uint2*)hsb1)[((size_t)(r0 + 2) * 32 + c4 * 2) >> 1] = make_uint2(pack2bf(a2.x, a2.y), pack2bf(a2.z, a2.w));
        if (r0 + 3 < n) ((uint2*)hsb1)[((size_t)(r0 + 3) * 32 + c4 * 2) >> 1] = make_uint2(pack2bf(a3.x, a3.y), pack2bf(a3.z, a3.w));
    }
}

// ---------------------------------------------------------------------------
// k_gg2: FUSED gather1+ReLU (per-edge dinv[src] weight, unscaled hsb1) and
// GEMM2 (W2 in LDS; output PRE-SCALED by dinv[node] -> k_gather stays clean).
// ---------------------------------------------------------------------------
__global__ __launch_bounds__(256) void k_gg2(const int* __restrict__ rowstart,
                                             const int* __restrict__ rowcnt,
                                             const unsigned short* __restrict__ edata,
                                             const uint32_t* __restrict__ hsb1,
                                             const float* __restrict__ dinv,
                                             const float* __restrict__ b1v,
                                             const float* __restrict__ W2,
                                             uint32_t* __restrict__ hsb2) {
    __shared__ float W2s[64 * 64];            // 16KB row-major [k][c]
    __shared__ float a1s[32][68];             // 8.7KB padded
    const int tid = threadIdx.x;

    for (int f = tid; f < 1024; f += 256)
        ((float4*)W2s)[f] = ((const float4*)W2)[f];

    // ---- phase A: gather (msg = dinv[s]*h1[s]) + self + bias + relu -> a1s
    const int nl = tid >> 3;
    const int lane = tid & 7;
    const int node = blockIdx.x * 32 + nl;
    if (node < N_NODES) {
        int start = rowstart[node];
        int end   = start + rowcnt[node];
        const uint4* hq = (const uint4*)hsb1;
        float a0 = 0.f, a1 = 0.f, a2 = 0.f, a3 = 0.f,
              a4 = 0.f, a5 = 0.f, a6 = 0.f, a7 = 0.f;
        int j = start;
        for (; j + 8 <= end; j += 8) {
            const int s0 = edata[j + 0];
            const int s1 = edata[j + 1];
            const int s2 = edata[j + 2];
            const int s3 = edata[j + 3];
            const int s4 = edata[j + 4];
            const int s5 = edata[j + 5];
            const int s6 = edata[j + 6];
            const int s7 = edata[j + 7];
            const float g0 = dinv[s0];
            const float g1 = dinv[s1];
            const float g2 = dinv[s2];
            const float g3 = dinv[s3];
            const float g4 = dinv[s4];
            const float g5 = dinv[s5];
            const float g6 = dinv[s6];
            const float g7 = dinv[s7];
            const uint4 v0 = hq[(size_t)s0 * 8 + lane];
            const uint4 v1 = hq[(size_t)s1 * 8 + lane];
            const uint4 v2 = hq[(size_t)s2 * 8 + lane];
            const uint4 v3 = hq[(size_t)s3 * 8 + lane];
            const uint4 v4 = hq[(size_t)s4 * 8 + lane];
            const uint4 v5 = hq[(size_t)s5 * 8 + lane];
            const uint4 v6 = hq[(size_t)s6 * 8 + lane];
            const uint4 v7 = hq[(size_t)s7 * 8 + lane];
            a0 += g0*bflo(v0.x) + g1*bflo(v1.x) + g2*bflo(v2.x) + g3*bflo(v3.x)
                + g4*bflo(v4.x) + g5*bflo(v5.x) + g6*bflo(v6.x) + g7*bflo(v7.x);
            a1 += g0*bfhi(v0.x) + g1*bfhi(v1.x) + g2*bfhi(v2.x) + g3*bfhi(v3.x)
                + g4*bfhi(v4.x) + g5*bfhi(v5.x) + g6*bfhi(v6.x) + g7*bfhi(v7.x);
            a2 += g0*bflo(v0.y) + g1*bflo(v1.y) + g2*bflo(v2.y) + g3*bflo(v3.y)
                + g4*bflo(v4.y) + g5*bflo(v5.y) + g6*bflo(v6.y) + g7*bflo(v7.y);
            a3 += g0*bfhi(v0.y) + g1*bfhi(v1.y) + g2*bfhi(v2.y) + g3*bfhi(v3.y)
                + g4*bfhi(v4.y) + g5*bfhi(v5.y) + g6*bfhi(v6.y) + g7*bfhi(v7.y);
            a4 += g0*bflo(v0.z) + g1*bflo(v1.z) + g2*bflo(v2.z) + g3*bflo(v3.z)
                + g4*bflo(v4.z) + g5*bflo(v5.z) + g6*bflo(v6.z) + g7*bflo(v7.z);
            a5 += g0*bfhi(v0.z) + g1*bfhi(v1.z) + g2*bfhi(v2.z) + g3*bfhi(v3.z)
                + g4*bfhi(v4.z) + g5*bfhi(v5.z) + g6*bfhi(v6.z) + g7*bfhi(v7.z);
            a6 += g0*bflo(v0.w) + g1*bflo(v1.w) + g2*bflo(v2.w) + g3*bflo(v3.w)
                + g4*bflo(v4.w) + g5*bflo(v5.w) + g6*bflo(v6.w) + g7*bflo(v7.w);
            a7 += g0*bfhi(v0.w) + g1*bfhi(v1.w) + g2*bfhi(v2.w) + g3*bfhi(v3.w)
                + g4*bfhi(v4.w) + g5*bfhi(v5.w) + g6*bfhi(v6.w) + g7*bfhi(v7.w);
        }
        for (; j < end; ++j) {
            const int s = edata[j];
            const float g = dinv[s];
            const uint4 v = hq[(size_t)s * 8 + lane];
            a0 += g * bflo(v.x); a1 += g * bfhi(v.x);
            a2 += g * bflo(v.y); a3 += g * bfhi(v.y);
            a4 += g * bflo(v.z); a5 += g * bfhi(v.z);
            a6 += g * bflo(v.w); a7 += g * bfhi(v.w);
        }
        const float di = dinv[node];
        {   // self loop: + dinv[node]*h1[node]
            const uint4 v = hq[(size_t)node * 8 + lane];
            a0 += di * bflo(v.x); a1 += di * bfhi(v.x);
            a2 += di * bflo(v.y); a3 += di * bfhi(v.y);
            a4 += di * bflo(v.z); a5 += di * bfhi(v.z);
            a6 += di * bflo(v.w); a7 += di * bfhi(v.w);
        }
        const float4 b0 = *reinterpret_cast<const float4*>(&b1v[lane * 8]);
        const float4 b1 = *reinterpret_cast<const float4*>(&b1v[lane * 8 + 4]);
        float4 o0, o1;
        o0.x = fmaxf(a0 * di + b0.x, 0.f);
        o0.y = fmaxf(a1 * di + b0.y, 0.f);
        o0.z = fmaxf(a2 * di + b0.z, 0.f);
        o0.w = fmaxf(a3 * di + b0.w, 0.f);
        o1.x = fmaxf(a4 * di + b1.x, 0.f);
        o1.y = fmaxf(a5 * di + b1.y, 0.f);
        o1.z = fmaxf(a6 * di + b1.z, 0.f);
        o1.w = fmaxf(a7 * di + b1.w, 0.f);
        *reinterpret_cast<float4*>(&a1s[nl][lane * 8])     = o0;
        *reinterpret_cast<float4*>(&a1s[nl][lane * 8 + 4]) = o1;
    }

    __syncthreads();

    // ---- phase B: hs2[node] = (a1s[node] @ W2) * dinv[node], packed bf16 ----
    const int gnode = blockIdx.x * 32 + (tid >> 3);
    if (gnode < N_NODES) {
        const int c8 = (tid & 7) * 8;
        const int nb = tid >> 3;
        float c0 = 0.f, c1 = 0.f, c2 = 0.f, c3 = 0.f,
              c4 = 0.f, c5 = 0.f, c6 = 0.f, c7 = 0.f;
#pragma unroll 8
        for (int k = 0; k < 64; ++k) {
            const float a = a1s[nb][k];
            const float4 w0 = *(const float4*)&W2s[k * 64 + c8];
            const float4 w1 = *(const float4*)&W2s[k * 64 + c8 + 4];
            c0 += a * w0.x; c1 += a * w0.y; c2 += a * w0.z; c3 += a * w0.w;
            c4 += a * w1.x; c5 += a * w1.y; c6 += a * w1.z; c7 += a * w1.w;
        }
        const float di = dinv[gnode];
        uint4 o;
        o.x = pack2bf(c0 * di, c1 * di);
        o.y = pack2bf(c2 * di, c3 * di);
        o.z = pack2bf(c4 * di, c5 * di);
        o.w = pack2bf(c6 * di, c7 * di);
        ((uint4*)hsb2)[(size_t)gnode * 8 + (tid & 7)] = o;
    }
}

// ---------------------------------------------------------------------------
// k_gather: layer-2 aggregate -> out (round-15 clean loop; hs2 pre-scaled).
// out[i] = dinv[i]*(sum_j hs2[j] + hs2[i]) + b2
// ---------------------------------------------------------------------------
__global__ __launch_bounds__(256) void k_gather(const int* __restrict__ rowstart,
                                                const int* __restrict__ rowcnt,
                                                const unsigned short* __restrict__ edata,
                                                const uint32_t* __restrict__ hsb,
                                                const float* __restrict__ dinv,
                                                const float* __restrict__ bias,
                                                float* __restrict__ out) {
    int node = blockIdx.x * 32 + (threadIdx.x >> 3);
    int lane = threadIdx.x & 7;
    if (node >= N_NODES) return;

    int start = rowstart[node];
    int end   = start + rowcnt[node];

    const uint4* hq = (const uint4*)hsb;
    float a0 = 0.f, a1 = 0.f, a2 = 0.f, a3 = 0.f,
          a4 = 0.f, a5 = 0.f, a6 = 0.f, a7 = 0.f;

    int j = start;
    for (; j + 8 <= end; j += 8) {
        const int s0 = edata[j + 0];
        const int s1 = edata[j + 1];
        const int s2 = edata[j + 2];
        const int s3 = edata[j + 3];
        const int s4 = edata[j + 4];
        const int s5 = edata[j + 5];
        const int s6 = edata[j + 6];
        const int s7 = edata[j + 7];
        const uint4 v0 = hq[(size_t)s0 * 8 + lane];
        const uint4 v1 = hq[(size_t)s1 * 8 + lane];
        const uint4 v2 = hq[(size_t)s2 * 8 + lane];
        const uint4 v3 = hq[(size_t)s3 * 8 + lane];
        const uint4 v4 = hq[(size_t)s4 * 8 + lane];
        const uint4 v5 = hq[(size_t)s5 * 8 + lane];
        const uint4 v6 = hq[(size_t)s6 * 8 + lane];
        const uint4 v7 = hq[(size_t)s7 * 8 + lane];
        a0 += ((bflo(v0.x) + bflo(v1.x)) + (bflo(v2.x) + bflo(v3.x)))
            + ((bflo(v4.x) + bflo(v5.x)) + (bflo(v6.x) + bflo(v7.x)));
        a1 += ((bfhi(v0.x) + bfhi(v1.x)) + (bfhi(v2.x) + bfhi(v3.x)))
            + ((bfhi(v4.x) + bfhi(v5.x)) + (bfhi(v6.x) + bfhi(v7.x)));
        a2 += ((bflo(v0.y) + bflo(v1.y)) + (bflo(v2.y) + bflo(v3.y)))
            + ((bflo(v4.y) + bflo(v5.y)) + (bflo(v6.y) + bflo(v7.y)));
        a3 += ((bfhi(v0.y) + bfhi(v1.y)) + (bfhi(v2.y) + bfhi(v3.y)))
            + ((bfhi(v4.y) + bfhi(v5.y)) + (bfhi(v6.y) + bfhi(v7.y)));
        a4 += ((bflo(v0.z) + bflo(v1.z)) + (bflo(v2.z) + bflo(v3.z)))
            + ((bflo(v4.z) + bflo(v5.z)) + (bflo(v6.z) + bflo(v7.z)));
        a5 += ((bfhi(v0.z) + bfhi(v1.z)) + (bfhi(v2.z) + bfhi(v3.z)))
            + ((bfhi(v4.z) + bfhi(v5.z)) + (bfhi(v6.z) + bfhi(v7.z)));
        a6 += ((bflo(v0.w) + bflo(v1.w)) + (bflo(v2.w) + bflo(v3.w)))
            + ((bflo(v4.w) + bflo(v5.w)) + (bflo(v6.w) + bflo(v7.w)));
        a7 += ((bfhi(v0.w) + bfhi(v1.w)) + (bfhi(v2.w) + bfhi(v3.w)))
            + ((bfhi(v4.w) + bfhi(v5.w)) + (bfhi(v6.w) + bfhi(v7.w)));
    }
    for (; j < end; ++j) {
        const int s = edata[j];
        const uint4 v = hq[(size_t)s * 8 + lane];
        a0 += bflo(v.x); a1 += bfhi(v.x);
        a2 += bflo(v.y); a3 += bfhi(v.y);
        a4 += bflo(v.z); a5 += bfhi(v.z);
        a6 += bflo(v.w); a7 += bfhi(v.w);
    }
    {   // self loop (hs2 already carries one dinv factor)
        const uint4 v = hq[(size_t)node * 8 + lane];
        a0 += bflo(v.x); a1 += bfhi(v.x);
        a2 += bflo(v.y); a3 += bfhi(v.y);
        a4 += bflo(v.z); a5 += bfhi(v.z);
        a6 += bflo(v.w); a7 += bfhi(v.w);
    }

    const float di = dinv[node];
    const float4 b0 = *reinterpret_cast<const float4*>(&bias[lane * 8]);
    const float4 b1 = *reinterpret_cast<const float4*>(&bias[lane * 8 + 4]);
    float4 o0, o1;
    o0.x = a0 * di + b0.x;  o0.y = a1 * di + b0.y;
    o0.z = a2 * di + b0.z;  o0.w = a3 * di + b0.w;
    o1.x = a4 * di + b1.x;  o1.y = a5 * di + b1.y;
    o1.z = a6 * di + b1.z;  o1.w = a7 * di + b1.w;
    float4* op = (float4*)&out[(size_t)node * 64 + lane * 8];
    op[0] = o0;
    op[1] = o1;
}

extern "C" void kernel_launch(void* const* d_in, const int* in_sizes, int n_in,
                              void* d_out, int out_size, void* d_ws, size_t ws_size,
                              hipStream_t stream) {
    const float* x  = (const float*)d_in[0];
    const int*   ei = (const int*)d_in[1];    // [2, N_EDGES] int32
    const float* W1 = (const float*)d_in[2];
    const float* b1 = (const float*)d_in[3];
    const float* W2 = (const float*)d_in[4];
    const float* b2 = (const float*)d_in[5];
    float* out = (float*)d_out;

    // Workspace carve-up (16B-aligned chunks):
    //   bucketcnt[128] | brec[NB*BCAP] | rowstart[N+4] | rowcnt[N+4] |
    //   edata ushort[NB*BCAP] | dinv[N] | hsb1[N*32 u32] | hsb2[N*32 u32]
    int*            bucketcnt = (int*)d_ws;
    int*            brec      = bucketcnt + 128;
    int*            rowstart  = brec + NB * BCAP;              // 1,003,520
    int*            rowcnt    = rowstart + (N_NODES + 4);
    unsigned short* edata     = (unsigned short*)(rowcnt + (N_NODES + 4));
    float*          dinv      = (float*)(edata + NB * BCAP);   // even count -> aligned
    uint32_t*       hsb1      = (uint32_t*)(dinv + N_NODES);   // bf16 [N][64]
    uint32_t*       hsb2      = hsb1 + (size_t)N_NODES * 32;   // bf16 [N][64]

    // --- CSR build + layer-1 GEMM (concurrent roles in one kernel) ---
    k_zc<<<1, 128, 0, stream>>>(bucketcnt);
    k_part2<<<NPB, 256, 0, stream>>>(ei, bucketcnt, brec);
    k_csrgemm<<<NB + GEMM_BLOCKS, 256, 0, stream>>>(brec, bucketcnt, rowstart, rowcnt,
                                                    dinv, edata, x, W1, hsb1, N_NODES);

    // --- fused gather1 + ReLU + GEMM2 ---
    k_gg2<<<(N_NODES + 31) / 32, 256, 0, stream>>>(rowstart, rowcnt, edata, hsb1, dinv, b1, W2, hsb2);
    // --- layer 2 aggregate ---
    k_gather<<<(N_NODES + 31) / 32, 256, 0, stream>>>(rowstart, rowcnt, edata, hsb2, dinv, b2, out);
}